// Round 1
// baseline (405.374 us; speedup 1.0000x reference)
//
#include <hip/hip_runtime.h>

#define F 64
#define SECAP 8192
#define TECAP 8192

// ---------------- K1: sort pos -> sel_id; per-output-slot (b, n) ----------------
__global__ void k1_setup(const int* __restrict__ pos, int B,
                         int* __restrict__ sel, int* __restrict__ slot_b,
                         int* __restrict__ slot_n) {
  if (threadIdx.x != 0 || blockIdx.x != 0) return;
  int p[64], s[64];
  for (int i = 0; i < B; ++i) { p[i] = pos[i]; s[i] = pos[i]; }
  // insertion sort (B=16 distinct values) -> sel_id ascending (jnp.unique order)
  for (int i = 1; i < B; ++i) {
    int v = s[i]; int j = i - 1;
    while (j >= 0 && s[j] > v) { s[j + 1] = s[j]; --j; }
    s[j + 1] = v;
  }
  for (int i = 0; i < B; ++i) sel[i] = s[i];
  // slot t=2m+j: node = pos[m,j]; batch = index of partner pos[m,1-j] in sel
  for (int t = 0; t < B; ++t) {
    int pv = p[t ^ 1];
    int b = 0;
    for (int i = 0; i < B; ++i) if (s[i] == pv) b = i;
    slot_b[t] = b;
    slot_n[t] = p[t];
  }
}

// ---------------- K2: base0 = x @ f0_w[0] + f0_b[0]  (N x 64) ----------------
__global__ __launch_bounds__(256) void k2_base0(const float* __restrict__ x,
                                                const float* __restrict__ W,
                                                const float* __restrict__ bias,
                                                float* __restrict__ base0, int N) {
  __shared__ float Wl[64][64];
  __shared__ float xr[4][64];
  int tx = threadIdx.x;        // col 0..63
  int ty = threadIdx.y;        // row-in-tile 0..3
  int tid = ty * 64 + tx;
  for (int i = tid; i < 4096; i += 256) Wl[i >> 6][i & 63] = W[i];
  int row = blockIdx.x * 4 + ty;
  if (row < N) xr[ty][tx] = x[(size_t)row * F + tx];
  __syncthreads();
  if (row < N) {
    float sum = bias[tx];
#pragma unroll
    for (int f = 0; f < 64; ++f) sum += xr[ty][f] * Wl[f][tx];
    base0[(size_t)row * F + tx] = sum;
  }
}

// ---------------- K3: one edge scan -> SE (src in sel) and TE (dst in targets) ----------------
__global__ __launch_bounds__(256) void k3_scan(const int* __restrict__ esrc,
                                               const int* __restrict__ edst,
                                               const float* __restrict__ ew, int E, int B,
                                               const int* __restrict__ sel,
                                               const int* __restrict__ slot_n,
                                               int* __restrict__ cnt,
                                               int* __restrict__ SEb, int* __restrict__ SEd,
                                               float* __restrict__ SEw,
                                               int* __restrict__ TEs, int* __restrict__ TEsrc,
                                               float* __restrict__ TEw) {
  __shared__ int selL[64], tnL[64];
  int tid = threadIdx.x;
  if (tid < B) { selL[tid] = sel[tid]; tnL[tid] = slot_n[tid]; }
  __syncthreads();
  int e = blockIdx.x * 256 + tid;
  if (e >= E) return;
  int s = esrc[e], d = edst[e];
  float w = ew[e];
  int bi = -1, ti = -1;
  for (int i = 0; i < B; ++i) {
    if (s == selL[i]) bi = i;
    if (d == tnL[i]) ti = i;
  }
  if (bi >= 0) {
    int idx = atomicAdd(&cnt[0], 1);
    if (idx < SECAP) { SEb[idx] = bi; SEd[idx] = d; SEw[idx] = w; }
  }
  if (ti >= 0) {
    int idx = atomicAdd(&cnt[1], 1);
    if (idx < TECAP) { TEs[idx] = ti; TEsrc[idx] = s; TEw[idx] = w; }
  }
}

// ---------------- K4a: build frontier = {TE srcs} U sel; assign compact slots ----------------
__global__ __launch_bounds__(256) void k4a_frontier(const int* __restrict__ sel,
                                                    const int* __restrict__ TEsrc,
                                                    const int* __restrict__ cnt, int B,
                                                    int* __restrict__ mark,
                                                    int* __restrict__ slot_of,
                                                    int* __restrict__ cntF, int fcap) {
  int i = blockIdx.x * 256 + threadIdx.x;
  int n;
  if (i < B) {
    n = sel[i];
  } else {
    int idx = i - B;
    int ten = min(cnt[1], TECAP);
    if (idx >= ten) return;
    n = TEsrc[idx];
  }
  int old = atomicAdd(&mark[n], 1);
  if (old == 0) {
    int s = atomicAdd(cntF, 1);
    slot_of[n] = s;
  }
}

// ---------------- K4b: AGG[slot(d)] += w * base0[src] for edges into frontier ----------------
__global__ __launch_bounds__(256) void k4b_agg(const int* __restrict__ esrc,
                                               const int* __restrict__ edst,
                                               const float* __restrict__ ew, int E,
                                               const int* __restrict__ mark,
                                               const int* __restrict__ slot_of,
                                               const float* __restrict__ base0,
                                               float* __restrict__ AGG, int fcap) {
  int e = blockIdx.x * 256 + threadIdx.x;
  if (e >= E) return;
  int d = edst[e];
  if (mark[d] == 0) return;
  int slot = slot_of[d];
  if ((unsigned)slot >= (unsigned)fcap) return;
  int s = esrc[e];
  float w = ew[e];
  const float4* src4 = (const float4*)(base0 + (size_t)s * F);
  float* dst = AGG + (size_t)slot * F;
#pragma unroll
  for (int i = 0; i < 16; ++i) {
    float4 v = src4[i];
    atomicAdd(dst + 4 * i + 0, w * v.x);
    atomicAdd(dst + 4 * i + 1, w * v.y);
    atomicAdd(dst + 4 * i + 2, w * v.z);
    atomicAdd(dst + 4 * i + 3, w * v.w);
  }
}

// ---------------- K5: z_f[slot] = AGG[slot] @ conv_w[0] + conv_b[0] (pre-ReLU) ----------------
__global__ __launch_bounds__(64) void k5_z(const float* __restrict__ AGG,
                                           const float* __restrict__ Wc0,
                                           const float* __restrict__ bc0,
                                           float* __restrict__ zf,
                                           const int* __restrict__ cnt, int fcap) {
  int slot = blockIdx.x;
  int Fn = min(cnt[2], fcap);
  if (slot >= Fn) return;
  __shared__ float a[64];
  int h = threadIdx.x;
  a[h] = AGG[(size_t)slot * F + h];
  __syncthreads();
  float sum = bc0[h];
#pragma unroll
  for (int f = 0; f < 64; ++f) sum += a[f] * Wc0[f * 64 + h];
  zf[(size_t)slot * F + h] = sum;
}

// ---------------- K6: per-batch small vectors: g0[b], x1_1[b] ----------------
__global__ __launch_bounds__(64) void k6_perb(const float* __restrict__ x,
                                              const float* __restrict__ base0,
                                              const float* __restrict__ f1w,
                                              const float* __restrict__ f1b,
                                              const float* __restrict__ cw,
                                              const int* __restrict__ sel,
                                              const int* __restrict__ slot_of,
                                              const int* __restrict__ SEb,
                                              const int* __restrict__ SEd,
                                              const float* __restrict__ SEw,
                                              const int* __restrict__ cnt,
                                              const float* __restrict__ zf,
                                              float* __restrict__ g0,
                                              float* __restrict__ x11, int fcap) {
  int b = blockIdx.x;
  int h = threadIdx.x;
  int node = sel[b];
  __shared__ float d0[64], h1s[64];
  // x1_0 = x[sel[b]] @ f1_w[0] + f1_b[0]
  float sum = f1b[h];
  const float* xr = x + (size_t)node * F;
#pragma unroll
  for (int f = 0; f < 64; ++f) sum += xr[f] * f1w[f * 64 + h];
  d0[h] = sum - base0[(size_t)node * F + h];
  __syncthreads();
  // g0 = d0 @ conv_w[0]
  float gs = 0.f;
#pragma unroll
  for (int f = 0; f < 64; ++f) gs += d0[f] * cw[f * 64 + h];
  g0[b * F + h] = gs;
  // c_self = sum of SE weights with (bi==b, dst==sel[b])  (self-edges of labeled node)
  float c = 0.f;
  int sen = min(cnt[0], SECAP);
  for (int i = 0; i < sen; ++i)
    if (SEb[i] == b && SEd[i] == node) c += SEw[i];
  int slot = slot_of[node];
  slot = min(max(slot, 0), fcap - 1);
  float z = zf[(size_t)slot * F + h] + c * gs;
  h1s[h] = fmaxf(z, 0.f);
  __syncthreads();
  // x1_1 = h1[b, sel[b]] @ f1_w[1] + f1_b[1]
  float s2 = f1b[64 + h];
#pragma unroll
  for (int f = 0; f < 64; ++f) s2 += h1s[f] * f1w[4096 + f * 64 + h];
  x11[b * F + h] = s2;
}

// ---------------- K7: per output slot: layer-1 agg at (b, n) -> out row ----------------
__global__ __launch_bounds__(64) void k7_out(const int* __restrict__ slot_b,
                                             const int* __restrict__ slot_n,
                                             const int* __restrict__ sel,
                                             const int* __restrict__ TEs,
                                             const int* __restrict__ TEsrc,
                                             const float* __restrict__ TEw,
                                             const int* __restrict__ SEb,
                                             const int* __restrict__ SEd,
                                             const float* __restrict__ SEw,
                                             const int* __restrict__ cnt,
                                             const int* __restrict__ slot_of,
                                             const float* __restrict__ zf,
                                             const float* __restrict__ g0,
                                             const float* __restrict__ x11,
                                             const float* __restrict__ f0w,
                                             const float* __restrict__ f0b,
                                             const float* __restrict__ cw,
                                             const float* __restrict__ cb,
                                             float* __restrict__ out, int fcap) {
  int t = blockIdx.x;
  int h = threadIdx.x;
  int b = slot_b[t];
  int seln = sel[b];
  int ten = min(cnt[1], TECAP), sen = min(cnt[0], SECAP);
  __shared__ float S[64], A[64];
  float s_h = 0.f;   // sum_{edges into n, src != sel[b]} w * h1[b,src][h]
  float wns = 0.f;   // sum of those w  (for the f0_b[1] bias term)
  float wsel = 0.f;  // sum of w over edges with src == sel[b]
  float gh = g0[b * F + h];
  for (int i = 0; i < ten; ++i) {
    if (TEs[i] != t) continue;           // uniform across block
    int s = TEsrc[i];
    float w = TEw[i];
    if (s == seln) { wsel += w; continue; }
    float c = 0.f;                        // layer-0 correction coeff c_{b,s}
    for (int j = 0; j < sen; ++j)
      if (SEb[j] == b && SEd[j] == s) c += SEw[j];
    int slot = slot_of[s];
    slot = min(max(slot, 0), fcap - 1);
    float h1 = fmaxf(zf[(size_t)slot * F + h] + c * gh, 0.f);
    s_h += w * h1;
    wns += w;
  }
  S[h] = s_h;
  __syncthreads();
  // agg1 = S @ f0_w[1] + wns * f0_b[1] + wsel * x1_1[b]
  float a = wns * f0b[64 + h] + wsel * x11[b * F + h];
#pragma unroll
  for (int f = 0; f < 64; ++f) a += S[f] * f0w[4096 + f * 64 + h];
  A[h] = a;
  __syncthreads();
  // out = agg1 @ conv_w[1] + conv_b[1]   (no relu on last layer)
  float o = cb[64 + h];
#pragma unroll
  for (int f = 0; f < 64; ++f) o += A[f] * cw[4096 + f * 64 + h];
  out[t * F + h] = o;
}

// ---------------- host-side workspace layout ----------------
struct Layout {
  size_t cnt, mark, agg, zero_bytes, sel, slotb, slotn, slotof,
      seb, sed, sew, tes, tesrc, tew, base0, zf, g0, x11, total;
};

static Layout make_layout(int N, int fcap) {
  Layout L;
  size_t off = 0;
  auto take = [&](size_t nb) {
    size_t r = off;
    off += (nb + 255) & ~(size_t)255;
    return r;
  };
  L.cnt = take(256);                       // counters: [0]=SE_n [1]=TE_n [2]=Fn
  L.mark = take((size_t)N * 4);            // zeroed
  L.agg = take((size_t)fcap * F * 4);      // zeroed
  L.zero_bytes = off;
  L.sel = take(256);
  L.slotb = take(256);
  L.slotn = take(256);
  L.slotof = take((size_t)N * 4);
  L.seb = take(SECAP * 4);
  L.sed = take(SECAP * 4);
  L.sew = take(SECAP * 4);
  L.tes = take(TECAP * 4);
  L.tesrc = take(TECAP * 4);
  L.tew = take(TECAP * 4);
  L.base0 = take((size_t)N * F * 4);
  L.zf = take((size_t)fcap * F * 4);
  L.g0 = take(64 * F * 4);
  L.x11 = take(64 * F * 4);
  L.total = off;
  return L;
}

extern "C" void kernel_launch(void* const* d_in, const int* in_sizes, int n_in,
                              void* d_out, int out_size, void* d_ws, size_t ws_size,
                              hipStream_t stream) {
  const float* x = (const float*)d_in[0];
  const int* pos = (const int*)d_in[1];
  const int* esrc = (const int*)d_in[2];
  const int* edst = (const int*)d_in[3];
  const float* ew = (const float*)d_in[4];
  const float* f0w = (const float*)d_in[5];
  const float* f0b = (const float*)d_in[6];
  const float* f1w = (const float*)d_in[7];
  const float* f1b = (const float*)d_in[8];
  const float* cw = (const float*)d_in[9];
  const float* cb = (const float*)d_in[10];
  float* out = (float*)d_out;

  const int N = in_sizes[0] / F;   // 10000
  const int B = in_sizes[1];       // 16 = 2*M
  const int E = in_sizes[2];       // 160000

  int fcap = TECAP + 16;           // frontier worst case: all TE srcs distinct + sel
  Layout L = make_layout(N, fcap);
  while (L.total > ws_size && fcap > 272) {
    fcap = fcap / 2 + 16;
    L = make_layout(N, fcap);
  }

  char* w = (char*)d_ws;
  int* cnt = (int*)(w + L.cnt);
  int* mark = (int*)(w + L.mark);
  float* AGG = (float*)(w + L.agg);
  int* sel = (int*)(w + L.sel);
  int* slotb = (int*)(w + L.slotb);
  int* slotn = (int*)(w + L.slotn);
  int* slotof = (int*)(w + L.slotof);
  int* SEb = (int*)(w + L.seb);
  int* SEd = (int*)(w + L.sed);
  float* SEw = (float*)(w + L.sew);
  int* TEs = (int*)(w + L.tes);
  int* TEsrc = (int*)(w + L.tesrc);
  float* TEw = (float*)(w + L.tew);
  float* base0 = (float*)(w + L.base0);
  float* zf = (float*)(w + L.zf);
  float* g0 = (float*)(w + L.g0);
  float* x11 = (float*)(w + L.x11);

  // zero counters + mark + AGG (one contiguous region at ws start)
  hipMemsetAsync(d_ws, 0, L.zero_bytes, stream);

  k1_setup<<<1, 64, 0, stream>>>(pos, B, sel, slotb, slotn);

  dim3 g2((N + 3) / 4), b2(64, 4);
  k2_base0<<<g2, b2, 0, stream>>>(x, f0w, f0b, base0, N);

  int eg = (E + 255) / 256;
  k3_scan<<<eg, 256, 0, stream>>>(esrc, edst, ew, E, B, sel, slotn, cnt,
                                  SEb, SEd, SEw, TEs, TEsrc, TEw);

  int fg = (B + TECAP + 255) / 256;
  k4a_frontier<<<fg, 256, 0, stream>>>(sel, TEsrc, cnt, B, mark, slotof, &cnt[2], fcap);

  k4b_agg<<<eg, 256, 0, stream>>>(esrc, edst, ew, E, mark, slotof, base0, AGG, fcap);

  k5_z<<<fcap, 64, 0, stream>>>(AGG, cw, cb, zf, cnt, fcap);

  k6_perb<<<B, 64, 0, stream>>>(x, base0, f1w, f1b, cw, sel, slotof,
                                SEb, SEd, SEw, cnt, zf, g0, x11, fcap);

  k7_out<<<B, 64, 0, stream>>>(slotb, slotn, sel, TEs, TEsrc, TEw,
                               SEb, SEd, SEw, cnt, slotof, zf, g0, x11,
                               f0w, f0b, cw, cb, out, fcap);
  (void)n_in; (void)out_size;
}

// Round 2
// 99.107 us; speedup vs baseline: 4.0903x; 4.0903x over previous
//
#include <hip/hip_runtime.h>

#define F 64
#define SECAP 8192
#define TECAP 8192

// ---------------- K1: sort pos -> sel_id; per-output-slot (b, n) ----------------
__global__ void k1_setup(const int* __restrict__ pos, int B,
                         int* __restrict__ sel, int* __restrict__ slot_b,
                         int* __restrict__ slot_n) {
  if (threadIdx.x != 0 || blockIdx.x != 0) return;
  int p[64], s[64];
  for (int i = 0; i < B; ++i) { p[i] = pos[i]; s[i] = pos[i]; }
  for (int i = 1; i < B; ++i) {           // insertion sort -> unique ascending
    int v = s[i]; int j = i - 1;
    while (j >= 0 && s[j] > v) { s[j + 1] = s[j]; --j; }
    s[j + 1] = v;
  }
  for (int i = 0; i < B; ++i) sel[i] = s[i];
  for (int t = 0; t < B; ++t) {           // slot t: node=pos[t], batch=rank of partner
    int pv = p[t ^ 1];
    int b = 0;
    for (int i = 0; i < B; ++i) if (s[i] == pv) b = i;
    slot_b[t] = b;
    slot_n[t] = p[t];
  }
}

// ---------------- K2: base0 = x @ f0_w[0] + f0_b[0]  (N x 64) ----------------
__global__ __launch_bounds__(256) void k2_base0(const float* __restrict__ x,
                                                const float* __restrict__ W,
                                                const float* __restrict__ bias,
                                                float* __restrict__ base0, int N) {
  __shared__ float Wl[64][64];
  __shared__ float xr[4][64];
  int tx = threadIdx.x, ty = threadIdx.y;
  int tid = ty * 64 + tx;
  for (int i = tid; i < 4096; i += 256) Wl[i >> 6][i & 63] = W[i];
  int row = blockIdx.x * 4 + ty;
  if (row < N) xr[ty][tx] = x[(size_t)row * F + tx];
  __syncthreads();
  if (row < N) {
    float sum = bias[tx];
#pragma unroll
    for (int f = 0; f < 64; ++f) sum += xr[ty][f] * Wl[f][tx];
    base0[(size_t)row * F + tx] = sum;
  }
}

// ---------------- K3: edge scan -> SE (src in sel) and TE (dst in targets) ----------------
__global__ __launch_bounds__(256) void k3_scan(const int* __restrict__ esrc,
                                               const int* __restrict__ edst,
                                               const float* __restrict__ ew, int E, int B,
                                               const int* __restrict__ sel,
                                               const int* __restrict__ slot_n,
                                               int* __restrict__ cnt,
                                               int* __restrict__ SEb, int* __restrict__ SEd,
                                               float* __restrict__ SEw,
                                               int* __restrict__ TEs, int* __restrict__ TEsrc,
                                               float* __restrict__ TEw) {
  __shared__ int selL[64], tnL[64];
  int tid = threadIdx.x;
  if (tid < B) { selL[tid] = sel[tid]; tnL[tid] = slot_n[tid]; }
  __syncthreads();
  int e = blockIdx.x * 256 + tid;
  if (e >= E) return;
  int s = esrc[e], d = edst[e];
  float w = ew[e];
  int bi = -1, ti = -1;
  for (int i = 0; i < B; ++i) {
    if (s == selL[i]) bi = i;
    if (d == tnL[i]) ti = i;
  }
  if (bi >= 0) {
    int idx = atomicAdd(&cnt[0], 1);
    if (idx < SECAP) { SEb[idx] = bi; SEd[idx] = d; SEw[idx] = w; }
  }
  if (ti >= 0) {
    int idx = atomicAdd(&cnt[1], 1);
    if (idx < TECAP) { TEs[idx] = ti; TEsrc[idx] = s; TEw[idx] = w; }
  }
}

// ---------------- K4a: frontier = {TE srcs} U sel; compact slot ids ----------------
__global__ __launch_bounds__(256) void k4a_frontier(const int* __restrict__ sel,
                                                    const int* __restrict__ TEsrc,
                                                    const int* __restrict__ cnt, int B,
                                                    int* __restrict__ mark,
                                                    int* __restrict__ slot_of,
                                                    int* __restrict__ cntF, int fcap) {
  int i = blockIdx.x * 256 + threadIdx.x;
  int n;
  if (i < B) {
    n = sel[i];
  } else {
    int idx = i - B;
    int ten = min(cnt[1], TECAP);
    if (idx >= ten) return;
    n = TEsrc[idx];
  }
  int old = atomicAdd(&mark[n], 1);
  if (old == 0) {
    int s = atomicAdd(cntF, 1);
    slot_of[n] = s;
  }
}

// ---------------- K4b: AGG[slot(d)] += w * base0[src] for edges into frontier ----------------
__global__ __launch_bounds__(256) void k4b_agg(const int* __restrict__ esrc,
                                               const int* __restrict__ edst,
                                               const float* __restrict__ ew, int E,
                                               const int* __restrict__ mark,
                                               const int* __restrict__ slot_of,
                                               const float* __restrict__ base0,
                                               float* __restrict__ AGG, int fcap) {
  int e = blockIdx.x * 256 + threadIdx.x;
  if (e >= E) return;
  int d = edst[e];
  if (mark[d] == 0) return;
  int slot = slot_of[d];
  if ((unsigned)slot >= (unsigned)fcap) return;
  int s = esrc[e];
  float w = ew[e];
  const float4* src4 = (const float4*)(base0 + (size_t)s * F);
  float* dst = AGG + (size_t)slot * F;
#pragma unroll
  for (int i = 0; i < 16; ++i) {
    float4 v = src4[i];
    atomicAdd(dst + 4 * i + 0, w * v.x);
    atomicAdd(dst + 4 * i + 1, w * v.y);
    atomicAdd(dst + 4 * i + 2, w * v.z);
    atomicAdd(dst + 4 * i + 3, w * v.w);
  }
}

// ---------------- K5: zf[slot] = AGG[slot] @ conv_w[0] + conv_b[0] (pre-ReLU) ----------------
__global__ __launch_bounds__(64) void k5_z(const float* __restrict__ AGG,
                                           const float* __restrict__ Wc0,
                                           const float* __restrict__ bc0,
                                           float* __restrict__ zf,
                                           const int* __restrict__ cnt, int fcap) {
  int slot = blockIdx.x;
  int Fn = min(cnt[2], fcap);
  if (slot >= Fn) return;
  __shared__ float a[64];
  int h = threadIdx.x;
  a[h] = AGG[(size_t)slot * F + h];
  __syncthreads();
  float sum = bc0[h];
#pragma unroll
  for (int f = 0; f < 64; ++f) sum += a[f] * Wc0[f * 64 + h];
  zf[(size_t)slot * F + h] = sum;
}

// ---------------- K5b: ctab[b][slot] = sum of SE weights landing on frontier node ----------------
__global__ __launch_bounds__(256) void k5b_ctab(const int* __restrict__ SEb,
                                                const int* __restrict__ SEd,
                                                const float* __restrict__ SEw,
                                                const int* __restrict__ cnt,
                                                const int* __restrict__ mark,
                                                const int* __restrict__ slot_of,
                                                float* __restrict__ ctab, int fcap) {
  int i = blockIdx.x * 256 + threadIdx.x;
  int sen = min(cnt[0], SECAP);
  if (i >= sen) return;
  int d = SEd[i];
  if (mark[d] == 0) return;      // c only needed at frontier nodes
  int slot = slot_of[d];
  if ((unsigned)slot >= (unsigned)fcap) return;
  atomicAdd(&ctab[(size_t)SEb[i] * fcap + slot], SEw[i]);
}

// ---------------- K6: per-batch vectors g0[b], x1_1[b] (ctab lookup, no scans) ----------------
__global__ __launch_bounds__(64) void k6_perb(const float* __restrict__ x,
                                              const float* __restrict__ base0,
                                              const float* __restrict__ f1w,
                                              const float* __restrict__ f1b,
                                              const float* __restrict__ cw,
                                              const int* __restrict__ sel,
                                              const int* __restrict__ slot_of,
                                              const float* __restrict__ ctab,
                                              const float* __restrict__ zf,
                                              float* __restrict__ g0,
                                              float* __restrict__ x11, int fcap) {
  int b = blockIdx.x;
  int h = threadIdx.x;
  int node = sel[b];
  __shared__ float d0[64], h1s[64];
  float sum = f1b[h];
  const float* xr = x + (size_t)node * F;
#pragma unroll
  for (int f = 0; f < 64; ++f) sum += xr[f] * f1w[f * 64 + h];
  d0[h] = sum - base0[(size_t)node * F + h];
  __syncthreads();
  float gs = 0.f;
#pragma unroll
  for (int f = 0; f < 64; ++f) gs += d0[f] * cw[f * 64 + h];
  g0[b * F + h] = gs;
  int slot = slot_of[node];
  slot = min(max(slot, 0), fcap - 1);
  float c = ctab[(size_t)b * fcap + slot];
  float z = zf[(size_t)slot * F + h] + c * gs;
  h1s[h] = fmaxf(z, 0.f);
  __syncthreads();
  float s2 = f1b[64 + h];
#pragma unroll
  for (int f = 0; f < 64; ++f) s2 += h1s[f] * f1w[4096 + f * 64 + h];
  x11[b * F + h] = s2;
}

// ---------------- K7a: parallel over TE entries -> scatter into Sbuf/wns/wsel ----------------
__global__ __launch_bounds__(256) void k7a_scatter(const int* __restrict__ TEs,
                                                   const int* __restrict__ TEsrc,
                                                   const float* __restrict__ TEw,
                                                   const int* __restrict__ slot_b,
                                                   const int* __restrict__ sel,
                                                   const int* __restrict__ cnt,
                                                   const int* __restrict__ slot_of,
                                                   const float* __restrict__ zf,
                                                   const float* __restrict__ g0,
                                                   const float* __restrict__ ctab,
                                                   float* __restrict__ Sbuf,
                                                   float* __restrict__ wns,
                                                   float* __restrict__ wsel, int fcap) {
  int idx = blockIdx.x * 4 + threadIdx.y;   // one TE entry per 64-lane row
  int h = threadIdx.x;
  int ten = min(cnt[1], TECAP);
  if (idx >= ten) return;
  int t = TEs[idx];
  int s = TEsrc[idx];
  float w = TEw[idx];
  int b = slot_b[t];
  if (s == sel[b]) {                        // labeled-source edge: handled via x11
    if (h == 0) atomicAdd(&wsel[t], w);
    return;
  }
  int slot = slot_of[s];
  slot = min(max(slot, 0), fcap - 1);
  float c = ctab[(size_t)b * fcap + slot];
  float h1 = fmaxf(zf[(size_t)slot * F + h] + c * g0[b * F + h], 0.f);
  atomicAdd(&Sbuf[t * F + h], w * h1);
  if (h == 0) atomicAdd(&wns[t], w);
}

// ---------------- K7b: per output slot: two 64x64 matvecs -> out row ----------------
__global__ __launch_bounds__(64) void k7b_out(const int* __restrict__ slot_b,
                                              const float* __restrict__ Sbuf,
                                              const float* __restrict__ wns,
                                              const float* __restrict__ wsel,
                                              const float* __restrict__ x11,
                                              const float* __restrict__ f0w,
                                              const float* __restrict__ f0b,
                                              const float* __restrict__ cw,
                                              const float* __restrict__ cb,
                                              float* __restrict__ out) {
  int t = blockIdx.x;
  int h = threadIdx.x;
  int b = slot_b[t];
  __shared__ float S[64], A[64];
  S[h] = Sbuf[t * F + h];
  float wn = wns[t], ws = wsel[t];
  __syncthreads();
  float a = wn * f0b[64 + h] + ws * x11[b * F + h];
#pragma unroll
  for (int f = 0; f < 64; ++f) a += S[f] * f0w[4096 + f * 64 + h];
  A[h] = a;
  __syncthreads();
  float o = cb[64 + h];
#pragma unroll
  for (int f = 0; f < 64; ++f) o += A[f] * cw[4096 + f * 64 + h];
  out[t * F + h] = o;
}

// ---------------- workspace layout ----------------
struct Layout {
  size_t cnt, mark, agg, ctab, sbuf, wns, wsel, zero_bytes,
      sel, slotb, slotn, slotof, seb, sed, sew, tes, tesrc, tew,
      base0, zf, g0, x11, total;
};

static Layout make_layout(int N, int B, int fcap) {
  Layout L;
  size_t off = 0;
  auto take = [&](size_t nb) {
    size_t r = off;
    off += (nb + 255) & ~(size_t)255;
    return r;
  };
  // ---- zeroed region (contiguous from 0) ----
  L.cnt = take(256);                          // [0]=SE_n [1]=TE_n [2]=Fn
  L.mark = take((size_t)N * 4);
  L.agg = take((size_t)fcap * F * 4);
  L.ctab = take((size_t)B * fcap * 4);
  L.sbuf = take((size_t)64 * F * 4);
  L.wns = take(256);
  L.wsel = take(256);
  L.zero_bytes = off;
  // ---- non-zeroed ----
  L.sel = take(256);
  L.slotb = take(256);
  L.slotn = take(256);
  L.slotof = take((size_t)N * 4);
  L.seb = take(SECAP * 4);
  L.sed = take(SECAP * 4);
  L.sew = take(SECAP * 4);
  L.tes = take(TECAP * 4);
  L.tesrc = take(TECAP * 4);
  L.tew = take(TECAP * 4);
  L.base0 = take((size_t)N * F * 4);
  L.zf = take((size_t)fcap * F * 4);
  L.g0 = take(64 * F * 4);
  L.x11 = take(64 * F * 4);
  L.total = off;
  return L;
}

extern "C" void kernel_launch(void* const* d_in, const int* in_sizes, int n_in,
                              void* d_out, int out_size, void* d_ws, size_t ws_size,
                              hipStream_t stream) {
  const float* x = (const float*)d_in[0];
  const int* pos = (const int*)d_in[1];
  const int* esrc = (const int*)d_in[2];
  const int* edst = (const int*)d_in[3];
  const float* ew = (const float*)d_in[4];
  const float* f0w = (const float*)d_in[5];
  const float* f0b = (const float*)d_in[6];
  const float* f1w = (const float*)d_in[7];
  const float* f1b = (const float*)d_in[8];
  const float* cw = (const float*)d_in[9];
  const float* cb = (const float*)d_in[10];
  float* out = (float*)d_out;

  const int N = in_sizes[0] / F;   // 10000
  const int B = in_sizes[1];       // 16 = 2*M
  const int E = in_sizes[2];       // 160000

  int fcap = TECAP + 64;
  Layout L = make_layout(N, B, fcap);
  while (L.total > ws_size && fcap > 272) {
    fcap = fcap / 2 + 64;
    L = make_layout(N, B, fcap);
  }

  char* w = (char*)d_ws;
  int* cnt = (int*)(w + L.cnt);
  int* mark = (int*)(w + L.mark);
  float* AGG = (float*)(w + L.agg);
  float* ctab = (float*)(w + L.ctab);
  float* Sbuf = (float*)(w + L.sbuf);
  float* wns = (float*)(w + L.wns);
  float* wsel = (float*)(w + L.wsel);
  int* sel = (int*)(w + L.sel);
  int* slotb = (int*)(w + L.slotb);
  int* slotn = (int*)(w + L.slotn);
  int* slotof = (int*)(w + L.slotof);
  int* SEb = (int*)(w + L.seb);
  int* SEd = (int*)(w + L.sed);
  float* SEw = (float*)(w + L.sew);
  int* TEs = (int*)(w + L.tes);
  int* TEsrc = (int*)(w + L.tesrc);
  float* TEw = (float*)(w + L.tew);
  float* base0 = (float*)(w + L.base0);
  float* zf = (float*)(w + L.zf);
  float* g0 = (float*)(w + L.g0);
  float* x11 = (float*)(w + L.x11);

  hipMemsetAsync(d_ws, 0, L.zero_bytes, stream);

  k1_setup<<<1, 64, 0, stream>>>(pos, B, sel, slotb, slotn);

  dim3 g2((N + 3) / 4), b2(64, 4);
  k2_base0<<<g2, b2, 0, stream>>>(x, f0w, f0b, base0, N);

  int eg = (E + 255) / 256;
  k3_scan<<<eg, 256, 0, stream>>>(esrc, edst, ew, E, B, sel, slotn, cnt,
                                  SEb, SEd, SEw, TEs, TEsrc, TEw);

  int fg = (B + TECAP + 255) / 256;
  k4a_frontier<<<fg, 256, 0, stream>>>(sel, TEsrc, cnt, B, mark, slotof, &cnt[2], fcap);

  k4b_agg<<<eg, 256, 0, stream>>>(esrc, edst, ew, E, mark, slotof, base0, AGG, fcap);

  k5_z<<<fcap, 64, 0, stream>>>(AGG, cw, cb, zf, cnt, fcap);

  k5b_ctab<<<(SECAP + 255) / 256, 256, 0, stream>>>(SEb, SEd, SEw, cnt, mark,
                                                    slotof, ctab, fcap);

  k6_perb<<<B, 64, 0, stream>>>(x, base0, f1w, f1b, cw, sel, slotof, ctab,
                                zf, g0, x11, fcap);

  dim3 g7a((TECAP + 3) / 4), b7a(64, 4);
  k7a_scatter<<<g7a, b7a, 0, stream>>>(TEs, TEsrc, TEw, slotb, sel, cnt,
                                       slotof, zf, g0, ctab, Sbuf, wns, wsel, fcap);

  k7b_out<<<B, 64, 0, stream>>>(slotb, Sbuf, wns, wsel, x11,
                                f0w, f0b, cw, cb, out);
  (void)n_in; (void)out_size;
}

// Round 3
// 61.460 us; speedup vs baseline: 6.5957x; 1.6125x over previous
//
#include <hip/hip_runtime.h>

#define F 64
#define SECAP 8192
#define TCAP 2048   // per-output-slot TE capacity

// ---------------- K0: zero {cnt, mark, TEn} + wave-parallel setup ----------------
__global__ __launch_bounds__(256) void k0_init(const int* __restrict__ pos, int B,
                                               int4* __restrict__ z0, int nz0_vec,
                                               int* __restrict__ sel,
                                               int* __restrict__ slotb,
                                               int* __restrict__ slotn) {
  int bid = blockIdx.x, tid = threadIdx.x;
  int i = bid * 256 + tid;
  if (i < nz0_vec) z0[i] = make_int4(0, 0, 0, 0);
  if (bid == (int)gridDim.x - 1) {
    __shared__ int ps[64];
    if (tid < B) ps[tid] = pos[tid];
    __syncthreads();
    if (tid < B) {
      int v = ps[tid];
      int pv = ps[tid ^ 1];
      int rank = 0, pr = 0;
      for (int j = 0; j < B; ++j) { rank += (ps[j] < v); pr += (ps[j] < pv); }
      sel[rank] = v;      // unique ascending (distinct values)
      slotb[tid] = pr;    // batch = rank of partner node
      slotn[tid] = v;     // target node of this output slot
    }
  }
}

// ---------------- K23: range A = GEMM base0, range B = edge scan (+sel mark),
// ----------------      range C = zero {AGG, ctab} ----------------
__global__ __launch_bounds__(256) void k23_main(
    const float* __restrict__ x, const float* __restrict__ f0w,
    const float* __restrict__ f0b, float* __restrict__ base0, int N,
    const int* __restrict__ esrc, const int* __restrict__ edst,
    const float* __restrict__ ew, int E, int B,
    const int* __restrict__ sel, const int* __restrict__ slotn,
    int* __restrict__ cnt, int* __restrict__ mark, int* __restrict__ slot_of,
    int* __restrict__ SEb, int* __restrict__ SEd, float* __restrict__ SEw,
    int* __restrict__ TEn, int* __restrict__ TEsrc2, float* __restrict__ TEw2,
    int4* __restrict__ z1, int nz1_vec, int nG, int nE) {
  int bid = blockIdx.x, tid = threadIdx.x;
  if (bid < nG) {                       // ---- GEMM: 4 rows per block ----
    __shared__ float Wl[64][64];
    __shared__ float xr[4][64];
    int tx = tid & 63, ty = tid >> 6;
    for (int i = tid; i < 4096; i += 256) Wl[i >> 6][i & 63] = f0w[i];
    int row = bid * 4 + ty;
    if (row < N) xr[ty][tx] = x[(size_t)row * F + tx];
    __syncthreads();
    if (row < N) {
      float sum = f0b[tx];
#pragma unroll
      for (int f = 0; f < 64; ++f) sum += xr[ty][f] * Wl[f][tx];
      base0[(size_t)row * F + tx] = sum;
    }
  } else if (bid < nG + nE) {           // ---- edge scan ----
    int ebi = bid - nG;
    __shared__ int selL[64], tnL[64];
    if (tid < B) { selL[tid] = sel[tid]; tnL[tid] = slotn[tid]; }
    __syncthreads();
    if (ebi == 0 && tid < B) {          // seed frontier with labeled nodes
      int n = selL[tid];
      int old = atomicAdd(&mark[n], 1);
      if (old == 0) slot_of[n] = atomicAdd(&cnt[2], 1);
    }
    int e = ebi * 256 + tid;
    if (e < E) {
      int s = esrc[e], d = edst[e];
      float w = ew[e];
      int bi = -1, ti = -1;
      for (int i = 0; i < B; ++i) {
        if (s == selL[i]) bi = i;
        if (d == tnL[i]) ti = i;
      }
      if (bi >= 0) {                    // src is a labeled node
        int idx = atomicAdd(&cnt[0], 1);
        if (idx < SECAP) { SEb[idx] = bi; SEd[idx] = d; SEw[idx] = w; }
      }
      if (ti >= 0) {                    // dst is an output target: bucket + mark src
        int idx = atomicAdd(&TEn[ti], 1);
        if (idx < TCAP) { TEsrc2[ti * TCAP + idx] = s; TEw2[ti * TCAP + idx] = w; }
        int old = atomicAdd(&mark[s], 1);
        if (old == 0) slot_of[s] = atomicAdd(&cnt[2], 1);
      }
    }
  } else {                              // ---- zero AGG + ctab ----
    int i = (bid - nG - nE) * 256 + tid;
    if (i < nz1_vec) z1[i] = make_int4(0, 0, 0, 0);
  }
}

// ---------------- K4b: AGG[slot(d)] += w * base0[src] for edges into frontier ----------------
__global__ __launch_bounds__(256) void k4b_agg(const int* __restrict__ esrc,
                                               const int* __restrict__ edst,
                                               const float* __restrict__ ew, int E,
                                               const int* __restrict__ mark,
                                               const int* __restrict__ slot_of,
                                               const float* __restrict__ base0,
                                               float* __restrict__ AGG, int fcap) {
  int e = blockIdx.x * 256 + threadIdx.x;
  if (e >= E) return;
  int d = edst[e];
  if (mark[d] == 0) return;
  int slot = slot_of[d];
  if ((unsigned)slot >= (unsigned)fcap) return;
  int s = esrc[e];
  float w = ew[e];
  const float4* src4 = (const float4*)(base0 + (size_t)s * F);
  float* dst = AGG + (size_t)slot * F;
#pragma unroll
  for (int i = 0; i < 16; ++i) {
    float4 v = src4[i];
    atomicAdd(dst + 4 * i + 0, w * v.x);
    atomicAdd(dst + 4 * i + 1, w * v.y);
    atomicAdd(dst + 4 * i + 2, w * v.z);
    atomicAdd(dst + 4 * i + 3, w * v.w);
  }
}

// ---------------- K55b: range A = zf matvec, range B = ctab scatter,
// ----------------       range C = TEslot precompute ----------------
__global__ __launch_bounds__(256) void k55b(
    const float* __restrict__ AGG, const float* __restrict__ cw,
    const float* __restrict__ cb, float* __restrict__ zf,
    const int* __restrict__ cnt, int fcap,
    const int* __restrict__ SEb, const int* __restrict__ SEd,
    const float* __restrict__ SEw,
    const int* __restrict__ mark, const int* __restrict__ slot_of,
    float* __restrict__ ctab,
    const int* __restrict__ TEn, const int* __restrict__ TEsrc2,
    const int* __restrict__ sel, const int* __restrict__ slotb,
    int* __restrict__ TEslot2, int B, int nA, int nB_) {
  int bid = blockIdx.x, tid = threadIdx.x;
  if (bid < nA) {                       // ---- zf[slot] = AGG[slot]@cw0 + cb0 ----
    int ty = tid >> 6, h = tid & 63;
    int slot = bid * 4 + ty;
    int Fn = min(cnt[2], fcap);
    if (slot >= Fn) return;
    __shared__ float a[4][64];
    a[ty][h] = AGG[(size_t)slot * F + h];   // same-wave LDS RAW: ordered, no barrier
    float sum = cb[h];
#pragma unroll
    for (int f = 0; f < 64; ++f) sum += a[ty][f] * cw[f * 64 + h];
    zf[(size_t)slot * F + h] = sum;
  } else if (bid < nA + nB_) {          // ---- ctab[b][slot(d)] += w ----
    int i = (bid - nA) * 256 + tid;
    int sen = min(cnt[0], SECAP);
    if (i >= sen) return;
    int d = SEd[i];
    if (mark[d] == 0) return;
    int slot = slot_of[d];
    if ((unsigned)slot >= (unsigned)fcap) return;
    atomicAdd(&ctab[(size_t)SEb[i] * fcap + slot], SEw[i]);
  } else {                              // ---- TEslot: src -> frontier slot (or -1) ----
    int idx = (bid - nA - nB_) * 256 + tid;
    int t = idx / TCAP, i = idx % TCAP;
    if (t >= B) return;
    int n = min(TEn[t], TCAP);
    if (i >= n) return;
    int s = TEsrc2[t * TCAP + i];
    int b = slotb[t];
    int ts;
    if (s == sel[b]) {
      ts = -1;                          // labeled-source edge -> x11 path
    } else {
      ts = slot_of[s];
      if ((unsigned)ts >= (unsigned)fcap) ts = 0;
    }
    TEslot2[t * TCAP + i] = ts;
  }
}

// ---------------- K7: per output slot, full epilogue (g0, x11, edge loop, 2 matvecs) ----------------
__global__ __launch_bounds__(64) void k7_final(
    const int* __restrict__ slotb, const int* __restrict__ sel,
    const int* __restrict__ slot_of,
    const float* __restrict__ x, const float* __restrict__ base0,
    const float* __restrict__ f1w, const float* __restrict__ f1b,
    const float* __restrict__ f0w, const float* __restrict__ f0b,
    const float* __restrict__ cw, const float* __restrict__ cb,
    const float* __restrict__ zf, const float* __restrict__ ctab,
    const int* __restrict__ TEn, const int* __restrict__ TEslot2,
    const float* __restrict__ TEw2,
    float* __restrict__ out, int fcap) {
  int t = blockIdx.x, h = threadIdx.x;
  int b = slotb[t];
  int seln = sel[b];
  __shared__ float sh[64];
  __shared__ int esl[TCAP];
  __shared__ float ewl[TCAP];
  int ten = min(TEn[t], TCAP);
  for (int i = h; i < ten; i += 64) {
    esl[i] = TEslot2[t * TCAP + i];
    ewl[i] = TEw2[t * TCAP + i];
  }
  // d0 = x[sel[b]] @ f1w[0] + f1b[0] - base0[sel[b]]
  sh[h] = x[(size_t)seln * F + h];
  __syncthreads();
  float acc = f1b[h];
#pragma unroll
  for (int f = 0; f < 64; ++f) acc += sh[f] * f1w[f * 64 + h];
  float d0h = acc - base0[(size_t)seln * F + h];
  __syncthreads();
  sh[h] = d0h;
  __syncthreads();
  // g0 = d0 @ conv_w[0]
  float g0h = 0.f;
#pragma unroll
  for (int f = 0; f < 64; ++f) g0h += sh[f] * cw[f * 64 + h];
  // h1 at the labeled node -> x11 = h1 @ f1_w[1] + f1_b[1]
  int sslot = slot_of[seln];
  if ((unsigned)sslot >= (unsigned)fcap) sslot = 0;
  float cself = ctab[(size_t)b * fcap + sslot];
  float h1self = fmaxf(zf[(size_t)sslot * F + h] + cself * g0h, 0.f);
  __syncthreads();
  sh[h] = h1self;
  __syncthreads();
  float x11h = f1b[64 + h];
#pragma unroll
  for (int f = 0; f < 64; ++f) x11h += sh[f] * f1w[4096 + f * 64 + h];
  // edge loop over this slot's TE bucket (LDS-staged, ~16 entries)
  float S = 0.f, wns = 0.f, wsel = 0.f;
  for (int i = 0; i < ten; ++i) {
    int slot = esl[i];
    float w = ewl[i];
    if (slot < 0) { wsel += w; continue; }
    float c = ctab[(size_t)b * fcap + slot];
    float h1 = fmaxf(zf[(size_t)slot * F + h] + c * g0h, 0.f);
    S += w * h1;
    wns += w;
  }
  __syncthreads();
  sh[h] = S;
  __syncthreads();
  // agg1 = S @ f0_w[1] + wns*f0_b[1] + wsel*x11
  float a2 = wns * f0b[64 + h] + wsel * x11h;
#pragma unroll
  for (int f = 0; f < 64; ++f) a2 += sh[f] * f0w[4096 + f * 64 + h];
  __syncthreads();
  sh[h] = a2;
  __syncthreads();
  // out = agg1 @ conv_w[1] + conv_b[1]
  float o = cb[64 + h];
#pragma unroll
  for (int f = 0; f < 64; ++f) o += sh[f] * cw[4096 + f * 64 + h];
  out[t * F + h] = o;
}

// ---------------- workspace layout ----------------
struct Layout {
  size_t cnt, mark, ten, z0_end,
      agg, ctab, z1_end,
      sel, slotb, slotn, slotof,
      seb, sed, sew, tesrc, tew, teslot,
      base0, zf, total;
};

static Layout make_layout(int N, int B, int fcap) {
  Layout L;
  size_t off = 0;
  auto take = [&](size_t nb) {
    size_t r = off;
    off += (nb + 255) & ~(size_t)255;
    return r;
  };
  // zeroed by k0:
  L.cnt = take(256);                    // [0]=SE count, [2]=frontier count
  L.mark = take((size_t)N * 4);
  L.ten = take(256);                    // per-slot TE counts (B ints)
  L.z0_end = off;
  // zeroed by k23 range C:
  L.agg = take((size_t)fcap * F * 4);
  L.ctab = take((size_t)B * fcap * 4);
  L.z1_end = off;
  // not zeroed:
  L.sel = take(256);
  L.slotb = take(256);
  L.slotn = take(256);
  L.slotof = take((size_t)N * 4);
  L.seb = take(SECAP * 4);
  L.sed = take(SECAP * 4);
  L.sew = take(SECAP * 4);
  L.tesrc = take((size_t)B * TCAP * 4);
  L.tew = take((size_t)B * TCAP * 4);
  L.teslot = take((size_t)B * TCAP * 4);
  L.base0 = take((size_t)N * F * 4);
  L.zf = take((size_t)fcap * F * 4);
  L.total = off;
  return L;
}

extern "C" void kernel_launch(void* const* d_in, const int* in_sizes, int n_in,
                              void* d_out, int out_size, void* d_ws, size_t ws_size,
                              hipStream_t stream) {
  const float* x = (const float*)d_in[0];
  const int* pos = (const int*)d_in[1];
  const int* esrc = (const int*)d_in[2];
  const int* edst = (const int*)d_in[3];
  const float* ew = (const float*)d_in[4];
  const float* f0w = (const float*)d_in[5];
  const float* f0b = (const float*)d_in[6];
  const float* f1w = (const float*)d_in[7];
  const float* f1b = (const float*)d_in[8];
  const float* cw = (const float*)d_in[9];
  const float* cb = (const float*)d_in[10];
  float* out = (float*)d_out;

  const int N = in_sizes[0] / F;   // 10000
  const int B = in_sizes[1];       // 16
  const int E = in_sizes[2];       // 160000

  int fcap = 8192 + 64;
  Layout L = make_layout(N, B, fcap);
  while (L.total > ws_size && fcap > 272) {
    fcap = fcap / 2 + 64;
    L = make_layout(N, B, fcap);
  }

  char* w = (char*)d_ws;
  int* cnt = (int*)(w + L.cnt);
  int* mark = (int*)(w + L.mark);
  int* TEn = (int*)(w + L.ten);
  float* AGG = (float*)(w + L.agg);
  float* ctab = (float*)(w + L.ctab);
  int* sel = (int*)(w + L.sel);
  int* slotb = (int*)(w + L.slotb);
  int* slotn = (int*)(w + L.slotn);
  int* slotof = (int*)(w + L.slotof);
  int* SEb = (int*)(w + L.seb);
  int* SEd = (int*)(w + L.sed);
  float* SEw = (float*)(w + L.sew);
  int* TEsrc2 = (int*)(w + L.tesrc);
  float* TEw2 = (float*)(w + L.tew);
  int* TEslot2 = (int*)(w + L.teslot);
  float* base0 = (float*)(w + L.base0);
  float* zf = (float*)(w + L.zf);

  // K0: zero {cnt,mark,TEn} + setup
  int nz0_vec = (int)(L.z0_end / 16);
  int nz0b = (nz0_vec + 255) / 256;
  k0_init<<<nz0b + 1, 256, 0, stream>>>(pos, B, (int4*)w, nz0_vec, sel, slotb, slotn);

  // K23: GEMM || edge scan || zero {AGG,ctab}
  int nG = (N + 3) / 4;
  int nE = (E + 255) / 256;
  int nz1_vec = (int)((L.z1_end - L.agg) / 16);
  int nZ = (nz1_vec + 255) / 256;
  k23_main<<<nG + nE + nZ, 256, 0, stream>>>(
      x, f0w, f0b, base0, N, esrc, edst, ew, E, B, sel, slotn,
      cnt, mark, slotof, SEb, SEd, SEw, TEn, TEsrc2, TEw2,
      (int4*)(w + L.agg), nz1_vec, nG, nE);

  // K4b: frontier aggregation
  k4b_agg<<<nE, 256, 0, stream>>>(esrc, edst, ew, E, mark, slotof, base0, AGG, fcap);

  // K55b: zf || ctab || TEslot
  int nA = (fcap + 3) / 4;
  int nB_ = SECAP / 256;
  int nC = (B * TCAP + 255) / 256;
  k55b<<<nA + nB_ + nC, 256, 0, stream>>>(AGG, cw, cb, zf, cnt, fcap,
                                          SEb, SEd, SEw, mark, slotof, ctab,
                                          TEn, TEsrc2, sel, slotb, TEslot2, B, nA, nB_);

  // K7: per-slot epilogue
  k7_final<<<B, 64, 0, stream>>>(slotb, sel, slotof, x, base0, f1w, f1b,
                                 f0w, f0b, cw, cb, zf, ctab, TEn, TEslot2, TEw2,
                                 out, fcap);
  (void)n_in; (void)out_size;
}